// Round 1
// baseline (1377.988 us; speedup 1.0000x reference)
//
#include <hip/hip_runtime.h>
#include <math.h>

// Problem constants: x [8,128,512,512] f32, 16 segments of 128x128.
#define B_     8
#define C_     128
#define H_     512
#define W_     512
#define HW_    (H_ * W_)          // 262144
#define NSEG_  16
#define TS_    128                // tile side
#define R_     16                 // output rows per strip (8 strips per tile)
#define LROWS_ (R_ + 2)           // 18 LDS rows incl. top/bottom halo
#define LSTR_  136                // LDS row stride in floats: 4 pad | 128 | 4 pad

// Fully fused: per-strip L2-over-channels into LDS, then tile-local 3x3 conv
// + bias + sigmoid from LDS. No workspace usage at all (avoids the 4 GiB
// ws-poison fill that was inside the timed window).
__global__ __launch_bounds__(256) void fused_kernel(const float* __restrict__ x,
                                                    const float* __restrict__ w,
                                                    const float* __restrict__ bias,
                                                    float* __restrict__ out) {
    __shared__ float l2s[LROWS_][LSTR_];

    const int tid = threadIdx.x;
    const int blk = blockIdx.x;              // 0..1023
    const int s   = blk & 7;                 // strip index within tile
    const int seg = (blk >> 3) & (NSEG_ - 1);
    const int b   = blk >> 7;
    const int ti  = seg >> 2;                // tile row in 4x4 grid
    const int tj  = seg & 3;                 // tile col

    // Uniform (block-constant) weights/bias -> scalar loads.
    const float* wp = w + seg * 9;
    const float w00 = wp[0], w01 = wp[1], w02 = wp[2];
    const float w10 = wp[3], w11 = wp[4], w12 = wp[5];
    const float w20 = wp[6], w21 = wp[7], w22 = wp[8];
    const float bb  = bias[seg];

    // Zero the left/right conv pads (data lives in cols [4,131]; conv reads [3,132]).
    if (tid < LROWS_) { l2s[tid][3] = 0.f; l2s[tid][4 + TS_] = 0.f; }

    // ---------- phase 1: L2 norm over channels, 18 rows x 128 cols ----------
    // float4-pixel index p in [0,576): rr = p>>5 (LDS row), c4 = p&31 (w/4).
    // Thread handles p = tid, tid+256, and (tid<64) tid+512.
    const int p0 = tid, p1 = tid + 256, p2 = tid + 512;
    const int rr0 = p0 >> 5, rr1 = p1 >> 5, rr2 = p2 >> 5;
    const int c40 = p0 & 31, c41 = p1 & 31, c42 = p2 & 31;
    const bool have2 = (tid < 64);

    const int ht0 = s * R_ + rr0 - 1;        // tile-row each LDS row maps to
    const int ht1 = s * R_ + rr1 - 1;        // always in [7,126] -> valid
    const int ht2 = s * R_ + rr2 - 1;
    const bool rv0 = (ht0 >= 0);             // false only for s=0, rr=0
    const bool rv2 = (ht2 <= TS_ - 1);       // false only for s=7, rr=17
    const int hc0 = rv0 ? ht0 : 0;           // clamp for address safety
    const int hc2 = rv2 ? ht2 : TS_ - 1;

    const size_t bbase = (size_t)b * C_ * HW_;
    const int wbase = tj * TS_;
    const int c0 = blk & (C_ - 1);           // per-block channel stagger

    const float* q0 = x + bbase + (size_t)c0 * HW_ + (size_t)(ti * TS_ + hc0) * W_ + wbase + c40 * 4;
    const float* q1 = x + bbase + (size_t)c0 * HW_ + (size_t)(ti * TS_ + ht1) * W_ + wbase + c41 * 4;
    const float* q2 = x + bbase + (size_t)c0 * HW_ + (size_t)(ti * TS_ + hc2) * W_ + wbase + c42 * 4;

    float4 a0 = make_float4(0.f, 0.f, 0.f, 0.f);
    float4 a1 = make_float4(0.f, 0.f, 0.f, 0.f);
    float4 a2 = make_float4(0.f, 0.f, 0.f, 0.f);

#define BODY                                                                      \
    {                                                                             \
        float4 v0 = *reinterpret_cast<const float4*>(q0); q0 += HW_;              \
        a0.x = fmaf(v0.x, v0.x, a0.x); a0.y = fmaf(v0.y, v0.y, a0.y);             \
        a0.z = fmaf(v0.z, v0.z, a0.z); a0.w = fmaf(v0.w, v0.w, a0.w);             \
        float4 v1 = *reinterpret_cast<const float4*>(q1); q1 += HW_;              \
        a1.x = fmaf(v1.x, v1.x, a1.x); a1.y = fmaf(v1.y, v1.y, a1.y);             \
        a1.z = fmaf(v1.z, v1.z, a1.z); a1.w = fmaf(v1.w, v1.w, a1.w);             \
        if (have2) {                                                              \
            float4 v2 = *reinterpret_cast<const float4*>(q2);                     \
            a2.x = fmaf(v2.x, v2.x, a2.x); a2.y = fmaf(v2.y, v2.y, a2.y);         \
            a2.z = fmaf(v2.z, v2.z, a2.z); a2.w = fmaf(v2.w, v2.w, a2.w);         \
        }                                                                         \
        q2 += HW_;                                                                \
    }

    const int n1 = C_ - c0;
#pragma unroll 4
    for (int i = 0; i < n1; ++i) BODY
    q0 -= (size_t)C_ * HW_;
    q1 -= (size_t)C_ * HW_;
    q2 -= (size_t)C_ * HW_;
#pragma unroll 4
    for (int i = 0; i < c0; ++i) BODY
#undef BODY

    float4 r0v, r1v;
    if (rv0) r0v = make_float4(sqrtf(a0.x), sqrtf(a0.y), sqrtf(a0.z), sqrtf(a0.w));
    else     r0v = make_float4(0.f, 0.f, 0.f, 0.f);
    r1v = make_float4(sqrtf(a1.x), sqrtf(a1.y), sqrtf(a1.z), sqrtf(a1.w));
    *reinterpret_cast<float4*>(&l2s[rr0][4 + c40 * 4]) = r0v;
    *reinterpret_cast<float4*>(&l2s[rr1][4 + c41 * 4]) = r1v;
    if (have2) {
        float4 r2v;
        if (rv2) r2v = make_float4(sqrtf(a2.x), sqrtf(a2.y), sqrtf(a2.z), sqrtf(a2.w));
        else     r2v = make_float4(0.f, 0.f, 0.f, 0.f);
        *reinterpret_cast<float4*>(&l2s[rr2][4 + c42 * 4]) = r2v;
    }

    __syncthreads();

    // ---------- phase 2: 3x3 conv (tile-local zero pad) + bias + sigmoid ----------
    const int c  = tid & (TS_ - 1);
    const int r2 = tid >> 7;                 // 0 or 1
    float* op = out + (((size_t)(b * NSEG_ + seg)) << 14) + ((size_t)(s * R_) << 7) + c;

#pragma unroll
    for (int k = 0; k < 8; ++k) {
        const int r = r2 + 2 * k;            // 0..15 within strip
        const float* L0 = &l2s[r    ][3 + c];
        const float* L1 = &l2s[r + 1][3 + c];
        const float* L2 = &l2s[r + 2][3 + c];
        float acc = bb;
        acc = fmaf(L0[0], w00, acc); acc = fmaf(L0[1], w01, acc); acc = fmaf(L0[2], w02, acc);
        acc = fmaf(L1[0], w10, acc); acc = fmaf(L1[1], w11, acc); acc = fmaf(L1[2], w12, acc);
        acc = fmaf(L2[0], w20, acc); acc = fmaf(L2[1], w21, acc); acc = fmaf(L2[2], w22, acc);
        op[(size_t)r << 7] = 1.0f / (1.0f + expf(-acc));
    }
}

extern "C" void kernel_launch(void* const* d_in, const int* in_sizes, int n_in,
                              void* d_out, int out_size, void* d_ws, size_t ws_size,
                              hipStream_t stream) {
    const float* x      = (const float*)d_in[0];
    const float* conv_w = (const float*)d_in[1];
    const float* conv_b = (const float*)d_in[2];
    float* out = (float*)d_out;

    // 1024 blocks = 8 batches x 16 segments x 8 strips; 256 threads each.
    fused_kernel<<<B_ * NSEG_ * 8, 256, 0, stream>>>(x, conv_w, conv_b, out);
}

// Round 2
// 1328.334 us; speedup vs baseline: 1.0374x; 1.0374x over previous
//
#include <hip/hip_runtime.h>
#include <math.h>

// Problem constants: x [8,128,512,512] f32, 16 segments of 128x128.
#define B_     8
#define C_     128
#define H_     512
#define W_     512
#define HW_    (H_ * W_)          // 262144 = 2^18
#define NSEG_  16
#define TS_    128                // tile side
#define SGRID_ 4                  // 4x4 tile grid

// ---------------------------------------------------------------------------
// Kernel 1: per-pixel L2 norm over channel dim, restructured for DRAM locality.
//
// Old layout read ~0.5-1 KB contiguous then jumped 1 MiB (channel stride) ->
// every chunk was a DRAM row-activate -> ~1.75 TB/s. Here each block owns
// 4096 CONTIGUOUS pixels (16 KB) and loops channels, so every jump is
// amortized over a 16 KB contiguous stream. 16 f32 accumulators/thread.
// ---------------------------------------------------------------------------
__global__ __launch_bounds__(256) void l2norm_kernel(const float* __restrict__ x,
                                                     float* __restrict__ l2) {
    const int tid = threadIdx.x;
    const int blk = blockIdx.x;              // 0..511
    const int px0 = blk << 12;               // 4096 pixels per block
    const int b   = px0 >> 18;               // batch (blocks never straddle batches)
    const int hw  = px0 & (HW_ - 1);

    const float* base = x + (size_t)b * C_ * HW_ + hw;

    float4 a0 = make_float4(0.f, 0.f, 0.f, 0.f);
    float4 a1 = make_float4(0.f, 0.f, 0.f, 0.f);
    float4 a2 = make_float4(0.f, 0.f, 0.f, 0.f);
    float4 a3 = make_float4(0.f, 0.f, 0.f, 0.f);

    // Per-block channel stagger so blocks don't all hit channel c at once.
    const int c0 = blk & (C_ - 1);
    const float* p = base + (size_t)c0 * HW_;

    // Byte offsets of this thread's 4 float4 groups within the 16 KB chunk.
    const int o0 = tid << 2;                 // floats
    const int o1 = o0 + 1024;
    const int o2 = o0 + 2048;
    const int o3 = o0 + 3072;

#define BODY                                                                   \
    {                                                                          \
        float4 v0 = *reinterpret_cast<const float4*>(p + o0);                  \
        float4 v1 = *reinterpret_cast<const float4*>(p + o1);                  \
        float4 v2 = *reinterpret_cast<const float4*>(p + o2);                  \
        float4 v3 = *reinterpret_cast<const float4*>(p + o3);                  \
        a0.x = fmaf(v0.x, v0.x, a0.x); a0.y = fmaf(v0.y, v0.y, a0.y);          \
        a0.z = fmaf(v0.z, v0.z, a0.z); a0.w = fmaf(v0.w, v0.w, a0.w);          \
        a1.x = fmaf(v1.x, v1.x, a1.x); a1.y = fmaf(v1.y, v1.y, a1.y);          \
        a1.z = fmaf(v1.z, v1.z, a1.z); a1.w = fmaf(v1.w, v1.w, a1.w);          \
        a2.x = fmaf(v2.x, v2.x, a2.x); a2.y = fmaf(v2.y, v2.y, a2.y);          \
        a2.z = fmaf(v2.z, v2.z, a2.z); a2.w = fmaf(v2.w, v2.w, a2.w);          \
        a3.x = fmaf(v3.x, v3.x, a3.x); a3.y = fmaf(v3.y, v3.y, a3.y);          \
        a3.z = fmaf(v3.z, v3.z, a3.z); a3.w = fmaf(v3.w, v3.w, a3.w);          \
        p += HW_;                                                              \
    }

    const int n1 = C_ - c0;
#pragma unroll 2
    for (int i = 0; i < n1; ++i) BODY
    p = base;
#pragma unroll 2
    for (int i = 0; i < c0; ++i) BODY
#undef BODY

    float4 r;
    float* o = l2 + px0;
    r = make_float4(sqrtf(a0.x), sqrtf(a0.y), sqrtf(a0.z), sqrtf(a0.w));
    *reinterpret_cast<float4*>(o + o0) = r;
    r = make_float4(sqrtf(a1.x), sqrtf(a1.y), sqrtf(a1.z), sqrtf(a1.w));
    *reinterpret_cast<float4*>(o + o1) = r;
    r = make_float4(sqrtf(a2.x), sqrtf(a2.y), sqrtf(a2.z), sqrtf(a2.w));
    *reinterpret_cast<float4*>(o + o2) = r;
    r = make_float4(sqrtf(a3.x), sqrtf(a3.y), sqrtf(a3.z), sqrtf(a3.w));
    *reinterpret_cast<float4*>(o + o3) = r;
}

// ---------------------------------------------------------------------------
// Kernel 2: per-tile 3x3 conv (zero pad at tile borders) + bias + sigmoid.
// Unchanged from the round-0 version (it was never the bottleneck; l2 map
// is L2/L3-resident). Output flat layout == [b][seg][r][c] row-major.
// ---------------------------------------------------------------------------
__global__ __launch_bounds__(256) void tileconv_kernel(const float* __restrict__ l2,
                                                       const float* __restrict__ w,
                                                       const float* __restrict__ bias,
                                                       float* __restrict__ out) {
    int t = blockIdx.x * blockDim.x + threadIdx.x;   // 0 .. B*NSEG*TS*TS-1
    int c   = t & (TS_ - 1);
    int r   = (t >> 7) & (TS_ - 1);
    int seg = (t >> 14) & (NSEG_ - 1);
    int b   = t >> 18;
    int ti = seg >> 2;      // tile row
    int tj = seg & 3;       // tile col

    const float* wp = w + seg * 9;
    float w00 = wp[0], w01 = wp[1], w02 = wp[2];
    float w10 = wp[3], w11 = wp[4], w12 = wp[5];
    float w20 = wp[6], w21 = wp[7], w22 = wp[8];

    const float* base = l2 + (size_t)b * HW_ + (size_t)(ti * TS_) * W_ + tj * TS_;

    float acc = bias[seg];
    bool up = (r > 0), dn = (r < TS_ - 1);
    bool lf = (c > 0), rt = (c < TS_ - 1);

    const float* row0 = base + (r - 1) * W_ + c;
    const float* row1 = row0 + W_;
    const float* row2 = row1 + W_;

    if (up) {
        if (lf) acc = fmaf(row0[-1], w00, acc);
        acc = fmaf(row0[0], w01, acc);
        if (rt) acc = fmaf(row0[1], w02, acc);
    }
    if (lf) acc = fmaf(row1[-1], w10, acc);
    acc = fmaf(row1[0], w11, acc);
    if (rt) acc = fmaf(row1[1], w12, acc);
    if (dn) {
        if (lf) acc = fmaf(row2[-1], w20, acc);
        acc = fmaf(row2[0], w21, acc);
        if (rt) acc = fmaf(row2[1], w22, acc);
    }

    out[t] = 1.0f / (1.0f + expf(-acc));
}

extern "C" void kernel_launch(void* const* d_in, const int* in_sizes, int n_in,
                              void* d_out, int out_size, void* d_ws, size_t ws_size,
                              hipStream_t stream) {
    const float* x      = (const float*)d_in[0];
    const float* conv_w = (const float*)d_in[1];
    const float* conv_b = (const float*)d_in[2];
    float* out = (float*)d_out;
    float* l2  = (float*)d_ws;   // 8 MB scratch (ws poison-fill happens regardless)

    // Kernel 1: 512 blocks x 256 threads, 16 px/thread, 16 KB contiguous/channel.
    l2norm_kernel<<<512, 256, 0, stream>>>(x, l2);

    // Kernel 2: one thread per output element.
    int n2 = B_ * NSEG_ * TS_ * TS_;       // 2097152
    tileconv_kernel<<<n2 / 256, 256, 0, stream>>>(l2, conv_w, conv_b, out);
}